// Round 4
// baseline (274.391 us; speedup 1.0000x reference)
//
#include <hip/hip_runtime.h>
#include <cstdint>

#define S_CNT 10000
#define R_CNT 10000
#define NT 50
#define PG 512            // p-groups = compute blocks
#define PROWS 98          // p-rows per group (512*98 = 50176 >= 50000)
#define KEYS_PER_G 128    // sub-key = t*2 + (s>=5000) < 100, padded to 128
#define NBINS (PG * KEYS_PER_G)   // 65536
#define PACKED_OFF_B (1 << 20)    // packed sample records start at 1 MiB in ws

// ---- pass 0: zero the histogram ----
__global__ __launch_bounds__(256) void zero_kernel(int4* __restrict__ cur4) {
    cur4[blockIdx.x * 256 + threadIdx.x] = make_int4(0, 0, 0, 0); // grid=64 -> 65536 ints
}

// ---- pass 1: histogram over (p-group, t, s-half) bins ----
__global__ __launch_bounds__(256) void hist_kernel(const int* __restrict__ X, int n,
                                                   int* __restrict__ cursors) {
    const int i = blockIdx.x * 256 + threadIdx.x;
    if (i < n) {
        const int4 x = *reinterpret_cast<const int4*>(X + 4ll * i);
        const int key = (x.z / PROWS) * KEYS_PER_G + x.w * 2 + (x.x >= 5000);
        atomicAdd(&cursors[key], 1);
    }
}

// ---- pass 2: exclusive scan of 65536 bins (single 1024-thread block) ----
__global__ __launch_bounds__(1024) void scan_kernel(const int* __restrict__ cursors,
                                                    int* __restrict__ cursors2,
                                                    int* __restrict__ offsets, int n) {
    __shared__ int part[1024];
    const int tid = threadIdx.x;
    const int base = tid * (NBINS / 1024);   // 64 bins per thread
    int sum = 0;
    for (int k = 0; k < NBINS / 1024; ++k) sum += cursors[base + k];
    part[tid] = sum;
    __syncthreads();
    for (int d = 1; d < 1024; d <<= 1) {
        const int v = (tid >= d) ? part[tid - d] : 0;
        __syncthreads();
        part[tid] += v;
        __syncthreads();
    }
    int run = part[tid] - sum;               // exclusive prefix of this thread's chunk
    for (int k = 0; k < NBINS / 1024; ++k) {
        const int c = cursors[base + k];
        offsets[base + k] = run;
        cursors2[base + k] = run;
        run += c;
    }
    if (tid == 1023) offsets[NBINS] = run;   // == n
}

// ---- pass 3: scatter packed records into bin order ----
__global__ __launch_bounds__(256) void scatter_kernel(const int* __restrict__ X, int n,
                                                      int* __restrict__ cursors2,
                                                      int4* __restrict__ packed) {
    const int i = blockIdx.x * 256 + threadIdx.x;
    if (i < n) {
        const int4 x = *reinterpret_cast<const int4*>(X + 4ll * i);
        const int key = (x.z / PROWS) * KEYS_PER_G + x.w * 2 + (x.x >= 5000);
        const int pos = atomicAdd(&cursors2[key], 1);
        packed[pos] = make_int4(x.x | (x.w << 16), x.y, x.z, i); // s|t<<16, r, p, idx
    }
}

// ---- pass 4: compute. One block per p-group; p-slice pinned in LDS. ----
__global__ __launch_bounds__(256) void compute_kernel(
    const int* __restrict__ offsets, const int4* __restrict__ packed,
    const float* __restrict__ s_embeds, const float* __restrict__ r_embeds,
    const float* __restrict__ p_embeds, float* __restrict__ out) {
    __shared__ __align__(16) float plds[PROWS * 128];  // 50176 B
    const int g = blockIdx.x;
    const int start = offsets[g * KEYS_PER_G];
    const int end   = offsets[(g + 1) * KEYS_PER_G];
    if (start >= end) return;

    const int prow0 = g * PROWS;
    const int rows = min(PROWS, 50000 - prow0);
    const int nf4 = rows * 32;               // rows*128/4 float4s
    const float4* src = reinterpret_cast<const float4*>(p_embeds + (long long)prow0 * 128);
    for (int k = threadIdx.x; k < nf4; k += 256)
        reinterpret_cast<float4*>(plds)[k] = src[k];
    __syncthreads();

    const int gl = threadIdx.x >> 4;   // group 0..15
    const int l  = threadIdx.x & 15;   // lane in group

    for (int sb = start; sb < end; sb += 32) {
        const int jA = sb + gl;
        const int jB = sb + 16 + gl;
        const int jAc = min(jA, end - 1);
        const int jBc = min(jB, end - 1);
        const int4 a = packed[jAc];
        const int4 b = packed[jBc];

        const int sA = a.x & 0xFFFF, tA = a.x >> 16;
        const int sB = b.x & 0xFFFF, tB = b.x >> 16;
        const int stA = sA + tA * S_CNT, rtA = a.y + tA * R_CNT;
        const int stB = sB + tB * S_CNT, rtB = b.y + tB * R_CNT;

        // issue all global gathers before any use (MLP)
        const float4 seA = *reinterpret_cast<const float4*>(s_embeds + (long long)stA * 64 + l * 4);
        const float4 reA = *reinterpret_cast<const float4*>(r_embeds + (long long)rtA * 64 + l * 4);
        const float4 seB = *reinterpret_cast<const float4*>(s_embeds + (long long)stB * 64 + l * 4);
        const float4 reB = *reinterpret_cast<const float4*>(r_embeds + (long long)rtB * 64 + l * 4);

        const int pA = (a.z - prow0) * 128;
        const int pB = (b.z - prow0) * 128;
        const float4 plA = *reinterpret_cast<const float4*>(plds + pA + l * 4);
        const float4 phA = *reinterpret_cast<const float4*>(plds + pA + 64 + l * 4);
        const float4 plB = *reinterpret_cast<const float4*>(plds + pB + l * 4);
        const float4 phB = *reinterpret_cast<const float4*>(plds + pB + 64 + l * 4);

        float accA = seA.x * plA.x + seA.y * plA.y + seA.z * plA.z + seA.w * plA.w
                   + reA.x * phA.x + reA.y * phA.y + reA.z * phA.z + reA.w * phA.w;
        float accB = seB.x * plB.x + seB.y * plB.y + seB.z * plB.z + seB.w * plB.w
                   + reB.x * phB.x + reB.y * phB.y + reB.z * phB.z + reB.w * phB.w;

        accA += __shfl_xor(accA, 1, 64);  accB += __shfl_xor(accB, 1, 64);
        accA += __shfl_xor(accA, 2, 64);  accB += __shfl_xor(accB, 2, 64);
        accA += __shfl_xor(accA, 4, 64);  accB += __shfl_xor(accB, 4, 64);
        accA += __shfl_xor(accA, 8, 64);  accB += __shfl_xor(accB, 8, 64);

        if (l == 0 && jA < end) out[a.w] = 1.0f / (1.0f + __expf(-accA));
        if (l == 0 && jB < end) out[b.w] = 1.0f / (1.0f + __expf(-accB));
    }
}

// ---- fallback: direct kernel (only if workspace too small) ----
__global__ __launch_bounds__(256) void direct_kernel(
    const int* __restrict__ X,
    const float* __restrict__ s_embeds, const float* __restrict__ r_embeds,
    const float* __restrict__ p_embeds, float* __restrict__ out, int n) {
    const int g = threadIdx.x >> 4;
    const int l = threadIdx.x & 15;
    const int i = blockIdx.x * 16 + g;
    if (i >= n) return;
    const int4 xi = *reinterpret_cast<const int4*>(X + 4ll * i);
    const long long st = (long long)xi.x + (long long)xi.w * S_CNT;
    const long long rt = (long long)xi.y + (long long)xi.w * R_CNT;
    const long long p  = xi.z;
    const float4 se = *reinterpret_cast<const float4*>(s_embeds + st * 64 + l * 4);
    const float4 re = *reinterpret_cast<const float4*>(r_embeds + rt * 64 + l * 4);
    const float4 pl = *reinterpret_cast<const float4*>(p_embeds + p * 128 + l * 4);
    const float4 ph = *reinterpret_cast<const float4*>(p_embeds + p * 128 + 64 + l * 4);
    float acc = se.x * pl.x + se.y * pl.y + se.z * pl.z + se.w * pl.w
              + re.x * ph.x + re.y * ph.y + re.z * ph.z + re.w * ph.w;
    acc += __shfl_xor(acc, 1, 64);
    acc += __shfl_xor(acc, 2, 64);
    acc += __shfl_xor(acc, 4, 64);
    acc += __shfl_xor(acc, 8, 64);
    if (l == 0) out[i] = 1.0f / (1.0f + __expf(-acc));
}

extern "C" void kernel_launch(void* const* d_in, const int* in_sizes, int n_in,
                              void* d_out, int out_size, void* d_ws, size_t ws_size,
                              hipStream_t stream) {
    const int*   X        = (const int*)d_in[0];
    const float* s_embeds = (const float*)d_in[1];
    const float* r_embeds = (const float*)d_in[2];
    const float* p_embeds = (const float*)d_in[3];
    float* out = (float*)d_out;
    const int n = in_sizes[0] / 4;

    const size_t ws_need = (size_t)PACKED_OFF_B + 16ull * (size_t)n;
    if (ws_size < ws_need) {
        direct_kernel<<<(n + 15) / 16, 256, 0, stream>>>(
            X, s_embeds, r_embeds, p_embeds, out, n);
        return;
    }

    int* wsI = (int*)d_ws;
    int* cursors  = wsI;                 // 65536 ints (histogram)
    int* cursors2 = wsI + NBINS;         // 65536 ints (scatter cursors)
    int* offsets  = wsI + 2 * NBINS;     // 65537 ints (bin start offsets)
    int4* packed  = reinterpret_cast<int4*>((char*)d_ws + PACKED_OFF_B);

    const int sgrid = (n + 255) / 256;
    zero_kernel<<<NBINS / 1024, 256, 0, stream>>>(reinterpret_cast<int4*>(cursors));
    hist_kernel<<<sgrid, 256, 0, stream>>>(X, n, cursors);
    scan_kernel<<<1, 1024, 0, stream>>>(cursors, cursors2, offsets, n);
    scatter_kernel<<<sgrid, 256, 0, stream>>>(X, n, cursors2, packed);
    compute_kernel<<<PG, 256, 0, stream>>>(
        offsets, packed, s_embeds, r_embeds, p_embeds, out);
}

// Round 5
// 148.842 us; speedup vs baseline: 1.8435x; 1.8435x over previous
//
#include <hip/hip_runtime.h>
#include <cstdint>

#define S_CNT 10000
#define R_CNT 10000
#define PG 1024            // p-groups
#define PROWS 49           // p-rows per group (1024*49 = 50176 >= 50000)
#define CAP 1216           // slots per group: E~977, sigma~31 -> +7.5 sigma
#define SPLIT 2            // compute blocks per group
#define PACKED_OFF_B 16384
#define WS_NEED ((size_t)PACKED_OFF_B + 16ull * PG * CAP)

// ---- pass 0: zero the group cursors (1024 ints) ----
__global__ __launch_bounds__(256) void zero_kernel(int4* __restrict__ cur4) {
    cur4[threadIdx.x] = make_int4(0, 0, 0, 0);
}

// ---- pass 1: single-pass bin-by-p-group scatter (block reservation) ----
__global__ __launch_bounds__(256) void bin_kernel(
    const int* __restrict__ X, int n, int* __restrict__ cursors,
    int4* __restrict__ packed,
    const float* __restrict__ se, const float* __restrict__ re,
    const float* __restrict__ pe, float* __restrict__ out)
{
    __shared__ int lhist[PG], lbase[PG], lcur[PG];
    const int tid = threadIdx.x;
    const long long base = (long long)blockIdx.x * 1024;

    #pragma unroll
    for (int k = 0; k < PG / 256; ++k) lhist[tid + 256 * k] = 0;
    __syncthreads();

    int4 xs[4];
    int  grp[4];
    #pragma unroll
    for (int it = 0; it < 4; ++it) {
        const long long i = base + it * 256 + tid;
        if (i < n) {
            xs[it] = *reinterpret_cast<const int4*>(X + 4 * i);
            grp[it] = xs[it].z / PROWS;
            atomicAdd(&lhist[grp[it]], 1);
        } else grp[it] = -1;
    }
    __syncthreads();
    #pragma unroll
    for (int k = 0; k < PG / 256; ++k) {
        const int b = tid + 256 * k;
        const int c = lhist[b];
        lbase[b] = c ? atomicAdd(&cursors[b], c) : 0;
        lcur[b] = 0;
    }
    __syncthreads();
    #pragma unroll
    for (int it = 0; it < 4; ++it) {
        const int g = grp[it];
        if (g < 0) continue;
        const long long i = base + it * 256 + tid;
        const int rank = lbase[g] + atomicAdd(&lcur[g], 1);
        if (rank < CAP) {
            packed[(long long)g * CAP + rank] =
                make_int4(xs[it].x | (xs[it].w << 16), xs[it].y, xs[it].z, (int)i);
        } else {
            // statistically unreachable overflow: compute sample directly
            const long long st = (long long)xs[it].x + (long long)xs[it].w * S_CNT;
            const long long rt = (long long)xs[it].y + (long long)xs[it].w * R_CNT;
            const long long p  = xs[it].z;
            float acc = 0.f;
            for (int k = 0; k < 64; ++k)
                acc += se[st * 64 + k] * pe[p * 128 + k]
                     + re[rt * 64 + k] * pe[p * 128 + 64 + k];
            out[i] = 1.0f / (1.0f + __expf(-acc));
        }
    }
}

// ---- pass 2: compute. SPLIT blocks per p-group; p-slice pinned in LDS. ----
__global__ __launch_bounds__(256) void compute_kernel(
    const int* __restrict__ cursors, const int4* __restrict__ packed,
    const float* __restrict__ s_embeds, const float* __restrict__ r_embeds,
    const float* __restrict__ p_embeds, float* __restrict__ out)
{
    __shared__ __align__(16) float plds[PROWS * 128];  // 25088 B
    const int g = blockIdx.x / SPLIT;
    const int q = blockIdx.x % SPLIT;
    const int cnt = min(cursors[g], CAP);
    if (cnt == 0) return;

    const int prow0 = g * PROWS;
    const int rows = min(PROWS, 50000 - prow0);
    const int nf4 = rows * 32;               // rows*128/4 float4s
    const float4* src = reinterpret_cast<const float4*>(p_embeds + (long long)prow0 * 128);
    for (int k = threadIdx.x; k < nf4; k += 256)
        reinterpret_cast<float4*>(plds)[k] = src[k];
    __syncthreads();

    const int lo  = (int)((long long)cnt * q / SPLIT);
    const int end = (int)((long long)cnt * (q + 1) / SPLIT);
    if (lo >= end) return;

    const int gl = threadIdx.x >> 4;   // group 0..15
    const int l  = threadIdx.x & 15;   // lane in group
    const int4* pk = packed + (long long)g * CAP;

    for (int sb = lo; sb < end; sb += 32) {
        const int jA = sb + gl;
        const int jB = sb + 16 + gl;
        const int4 a = pk[min(jA, end - 1)];
        const int4 b = pk[min(jB, end - 1)];

        const int sA = a.x & 0xFFFF, tA = a.x >> 16;
        const int sB = b.x & 0xFFFF, tB = b.x >> 16;
        const int stA = sA + tA * S_CNT, rtA = a.y + tA * R_CNT;
        const int stB = sB + tB * S_CNT, rtB = b.y + tB * R_CNT;

        // issue all global gathers before any use (MLP)
        const float4 seA = *reinterpret_cast<const float4*>(s_embeds + (long long)stA * 64 + l * 4);
        const float4 reA = *reinterpret_cast<const float4*>(r_embeds + (long long)rtA * 64 + l * 4);
        const float4 seB = *reinterpret_cast<const float4*>(s_embeds + (long long)stB * 64 + l * 4);
        const float4 reB = *reinterpret_cast<const float4*>(r_embeds + (long long)rtB * 64 + l * 4);

        const int pA = (a.z - prow0) * 128;
        const int pB = (b.z - prow0) * 128;
        const float4 plA = *reinterpret_cast<const float4*>(plds + pA + l * 4);
        const float4 phA = *reinterpret_cast<const float4*>(plds + pA + 64 + l * 4);
        const float4 plB = *reinterpret_cast<const float4*>(plds + pB + l * 4);
        const float4 phB = *reinterpret_cast<const float4*>(plds + pB + 64 + l * 4);

        float accA = seA.x * plA.x + seA.y * plA.y + seA.z * plA.z + seA.w * plA.w
                   + reA.x * phA.x + reA.y * phA.y + reA.z * phA.z + reA.w * phA.w;
        float accB = seB.x * plB.x + seB.y * plB.y + seB.z * plB.z + seB.w * plB.w
                   + reB.x * phB.x + reB.y * phB.y + reB.z * phB.z + reB.w * phB.w;

        accA += __shfl_xor(accA, 1, 64);  accB += __shfl_xor(accB, 1, 64);
        accA += __shfl_xor(accA, 2, 64);  accB += __shfl_xor(accB, 2, 64);
        accA += __shfl_xor(accA, 4, 64);  accB += __shfl_xor(accB, 4, 64);
        accA += __shfl_xor(accA, 8, 64);  accB += __shfl_xor(accB, 8, 64);

        if (l == 0 && jA < end) out[a.w] = 1.0f / (1.0f + __expf(-accA));
        if (l == 0 && jB < end) out[b.w] = 1.0f / (1.0f + __expf(-accB));
    }
}

// ---- fallback: direct kernel (only if workspace too small) ----
__global__ __launch_bounds__(256) void direct_kernel(
    const int* __restrict__ X,
    const float* __restrict__ s_embeds, const float* __restrict__ r_embeds,
    const float* __restrict__ p_embeds, float* __restrict__ out, int n) {
    const int g = threadIdx.x >> 4;
    const int l = threadIdx.x & 15;
    const int i = blockIdx.x * 16 + g;
    if (i >= n) return;
    const int4 xi = *reinterpret_cast<const int4*>(X + 4ll * i);
    const long long st = (long long)xi.x + (long long)xi.w * S_CNT;
    const long long rt = (long long)xi.y + (long long)xi.w * R_CNT;
    const long long p  = xi.z;
    const float4 se = *reinterpret_cast<const float4*>(s_embeds + st * 64 + l * 4);
    const float4 re = *reinterpret_cast<const float4*>(r_embeds + rt * 64 + l * 4);
    const float4 pl = *reinterpret_cast<const float4*>(p_embeds + p * 128 + l * 4);
    const float4 ph = *reinterpret_cast<const float4*>(p_embeds + p * 128 + 64 + l * 4);
    float acc = se.x * pl.x + se.y * pl.y + se.z * pl.z + se.w * pl.w
              + re.x * ph.x + re.y * ph.y + re.z * ph.z + re.w * ph.w;
    acc += __shfl_xor(acc, 1, 64);
    acc += __shfl_xor(acc, 2, 64);
    acc += __shfl_xor(acc, 4, 64);
    acc += __shfl_xor(acc, 8, 64);
    if (l == 0) out[i] = 1.0f / (1.0f + __expf(-acc));
}

extern "C" void kernel_launch(void* const* d_in, const int* in_sizes, int n_in,
                              void* d_out, int out_size, void* d_ws, size_t ws_size,
                              hipStream_t stream) {
    const int*   X        = (const int*)d_in[0];
    const float* s_embeds = (const float*)d_in[1];
    const float* r_embeds = (const float*)d_in[2];
    const float* p_embeds = (const float*)d_in[3];
    float* out = (float*)d_out;
    const int n = in_sizes[0] / 4;

    if (ws_size < WS_NEED) {
        direct_kernel<<<(n + 15) / 16, 256, 0, stream>>>(
            X, s_embeds, r_embeds, p_embeds, out, n);
        return;
    }

    int* cursors = (int*)d_ws;
    int4* packed = reinterpret_cast<int4*>((char*)d_ws + PACKED_OFF_B);

    zero_kernel<<<1, 256, 0, stream>>>(reinterpret_cast<int4*>(cursors));
    bin_kernel<<<(n + 1023) / 1024, 256, 0, stream>>>(
        X, n, cursors, packed, s_embeds, r_embeds, p_embeds, out);
    compute_kernel<<<PG * SPLIT, 256, 0, stream>>>(
        cursors, packed, s_embeds, r_embeds, p_embeds, out);
}

// Round 6
// 141.576 us; speedup vs baseline: 1.9381x; 1.0513x over previous
//
#include <hip/hip_runtime.h>
#include <cstdint>

#define S_CNT 10000
#define R_CNT 10000
#define PG 1024            // p-groups
#define PROWS 49           // p-rows per group (1024*49 = 50176 >= 50000)
#define CAP 1216           // slots per group: E~977, sigma~31 -> +7.5 sigma
#define SPLIT 2            // compute blocks per group -> grid 2048 = exact residency
#define PACKED_OFF_B 16384
#define WS_NEED ((size_t)PACKED_OFF_B + 16ull * PG * CAP)

__device__ __forceinline__ unsigned bfpack(float a, float b) {
    unsigned ua = __float_as_uint(a), ub = __float_as_uint(b);
    ua = (ua + 0x7FFFu + ((ua >> 16) & 1u)) >> 16;       // round-to-nearest-even bf16
    ub = (ub + 0x7FFFu + ((ub >> 16) & 1u)) >> 16;
    return ua | (ub << 16);
}
__device__ __forceinline__ float blo(unsigned u) { return __uint_as_float(u << 16); }
__device__ __forceinline__ float bhi(unsigned u) { return __uint_as_float(u & 0xFFFF0000u); }

// ---- pass 0: zero the group cursors (1024 ints) ----
__global__ __launch_bounds__(256) void zero_kernel(int4* __restrict__ cur4) {
    cur4[threadIdx.x] = make_int4(0, 0, 0, 0);
}

// ---- pass 1: single-pass bin-by-p-group scatter (block reservation) ----
__global__ __launch_bounds__(256) void bin_kernel(
    const int* __restrict__ X, int n, int* __restrict__ cursors,
    int4* __restrict__ packed,
    const float* __restrict__ se, const float* __restrict__ re,
    const float* __restrict__ pe, float* __restrict__ out)
{
    __shared__ int lhist[PG], lbase[PG], lcur[PG];
    const int tid = threadIdx.x;
    const long long base = (long long)blockIdx.x * 1024;

    #pragma unroll
    for (int k = 0; k < PG / 256; ++k) lhist[tid + 256 * k] = 0;
    __syncthreads();

    int4 xs[4];
    int  grp[4];
    #pragma unroll
    for (int it = 0; it < 4; ++it) {
        const long long i = base + it * 256 + tid;
        if (i < n) {
            xs[it] = *reinterpret_cast<const int4*>(X + 4 * i);
            grp[it] = xs[it].z / PROWS;
            atomicAdd(&lhist[grp[it]], 1);
        } else grp[it] = -1;
    }
    __syncthreads();
    #pragma unroll
    for (int k = 0; k < PG / 256; ++k) {
        const int b = tid + 256 * k;
        const int c = lhist[b];
        lbase[b] = c ? atomicAdd(&cursors[b], c) : 0;
        lcur[b] = 0;
    }
    __syncthreads();
    #pragma unroll
    for (int it = 0; it < 4; ++it) {
        const int g = grp[it];
        if (g < 0) continue;
        const long long i = base + it * 256 + tid;
        const int rank = lbase[g] + atomicAdd(&lcur[g], 1);
        if (rank < CAP) {
            packed[(long long)g * CAP + rank] =
                make_int4(xs[it].x | (xs[it].w << 16), xs[it].y, xs[it].z, (int)i);
        } else {
            // statistically unreachable overflow: compute sample directly
            const long long st = (long long)xs[it].x + (long long)xs[it].w * S_CNT;
            const long long rt = (long long)xs[it].y + (long long)xs[it].w * R_CNT;
            const long long p  = xs[it].z;
            float acc = 0.f;
            for (int k = 0; k < 64; ++k)
                acc += se[st * 64 + k] * pe[p * 128 + k]
                     + re[rt * 64 + k] * pe[p * 128 + 64 + k];
            out[i] = 1.0f / (1.0f + __expf(-acc));
        }
    }
}

// ---- pass 2: compute. p-slice pinned in LDS as bf16 (12.5 KB) -> 8 blocks/CU ----
__global__ __launch_bounds__(256, 8) void compute_kernel(
    const int* __restrict__ cursors, const int4* __restrict__ packed,
    const float* __restrict__ s_embeds, const float* __restrict__ r_embeds,
    const float* __restrict__ p_embeds, float* __restrict__ out)
{
    __shared__ __align__(16) unsigned plds[PROWS * 64];  // bf16x2, 12544 B
    const int g = blockIdx.x / SPLIT;
    const int q = blockIdx.x % SPLIT;
    const int cnt = min(cursors[g], CAP);
    if (cnt == 0) return;

    const int prow0 = g * PROWS;
    const int rows = min(PROWS, 50000 - prow0);
    const int nf4 = rows * 32;               // float4s to stage
    const float4* src = reinterpret_cast<const float4*>(p_embeds + (long long)prow0 * 128);
    for (int k = threadIdx.x; k < nf4; k += 256) {
        const float4 v = src[k];
        uint2 u;
        u.x = bfpack(v.x, v.y);
        u.y = bfpack(v.z, v.w);
        reinterpret_cast<uint2*>(plds)[k] = u;
    }
    __syncthreads();

    const int lo  = (int)((long long)cnt * q / SPLIT);
    const int end = (int)((long long)cnt * (q + 1) / SPLIT);
    if (lo >= end) return;

    const int gl = threadIdx.x >> 4;   // group 0..15
    const int l  = threadIdx.x & 15;   // lane in group
    const int4* pk = packed + (long long)g * CAP;

    for (int sb = lo; sb < end; sb += 32) {
        const int jA = sb + gl;
        const int jB = sb + 16 + gl;
        const int4 a = pk[min(jA, end - 1)];
        const int4 b = pk[min(jB, end - 1)];

        const int sA = a.x & 0xFFFF, tA = a.x >> 16;
        const int sB = b.x & 0xFFFF, tB = b.x >> 16;
        const int stA = sA + tA * S_CNT, rtA = a.y + tA * R_CNT;
        const int stB = sB + tB * S_CNT, rtB = b.y + tB * R_CNT;

        // issue all global gathers before any use (MLP)
        const float4 seA = *reinterpret_cast<const float4*>(s_embeds + (long long)stA * 64 + l * 4);
        const float4 reA = *reinterpret_cast<const float4*>(r_embeds + (long long)rtA * 64 + l * 4);
        const float4 seB = *reinterpret_cast<const float4*>(s_embeds + (long long)stB * 64 + l * 4);
        const float4 reB = *reinterpret_cast<const float4*>(r_embeds + (long long)rtB * 64 + l * 4);

        // p fragments from LDS (bf16x2 pairs): row*64 u32 base, low half l*2, high +32
        const int pA32 = (a.z - prow0) * 64;
        const int pB32 = (b.z - prow0) * 64;
        const uint2 uplA = *reinterpret_cast<const uint2*>(&plds[pA32 + l * 2]);
        const uint2 uphA = *reinterpret_cast<const uint2*>(&plds[pA32 + 32 + l * 2]);
        const uint2 uplB = *reinterpret_cast<const uint2*>(&plds[pB32 + l * 2]);
        const uint2 uphB = *reinterpret_cast<const uint2*>(&plds[pB32 + 32 + l * 2]);

        float accA = seA.x * blo(uplA.x) + seA.y * bhi(uplA.x)
                   + seA.z * blo(uplA.y) + seA.w * bhi(uplA.y)
                   + reA.x * blo(uphA.x) + reA.y * bhi(uphA.x)
                   + reA.z * blo(uphA.y) + reA.w * bhi(uphA.y);
        float accB = seB.x * blo(uplB.x) + seB.y * bhi(uplB.x)
                   + seB.z * blo(uplB.y) + seB.w * bhi(uplB.y)
                   + reB.x * blo(uphB.x) + reB.y * bhi(uphB.x)
                   + reB.z * blo(uphB.y) + reB.w * bhi(uphB.y);

        accA += __shfl_xor(accA, 1, 64);  accB += __shfl_xor(accB, 1, 64);
        accA += __shfl_xor(accA, 2, 64);  accB += __shfl_xor(accB, 2, 64);
        accA += __shfl_xor(accA, 4, 64);  accB += __shfl_xor(accB, 4, 64);
        accA += __shfl_xor(accA, 8, 64);  accB += __shfl_xor(accB, 8, 64);

        if (l == 0 && jA < end) out[a.w] = 1.0f / (1.0f + __expf(-accA));
        if (l == 0 && jB < end) out[b.w] = 1.0f / (1.0f + __expf(-accB));
    }
}

// ---- fallback: direct kernel (only if workspace too small) ----
__global__ __launch_bounds__(256) void direct_kernel(
    const int* __restrict__ X,
    const float* __restrict__ s_embeds, const float* __restrict__ r_embeds,
    const float* __restrict__ p_embeds, float* __restrict__ out, int n) {
    const int g = threadIdx.x >> 4;
    const int l = threadIdx.x & 15;
    const int i = blockIdx.x * 16 + g;
    if (i >= n) return;
    const int4 xi = *reinterpret_cast<const int4*>(X + 4ll * i);
    const long long st = (long long)xi.x + (long long)xi.w * S_CNT;
    const long long rt = (long long)xi.y + (long long)xi.w * R_CNT;
    const long long p  = xi.z;
    const float4 se = *reinterpret_cast<const float4*>(s_embeds + st * 64 + l * 4);
    const float4 re = *reinterpret_cast<const float4*>(r_embeds + rt * 64 + l * 4);
    const float4 pl = *reinterpret_cast<const float4*>(p_embeds + p * 128 + l * 4);
    const float4 ph = *reinterpret_cast<const float4*>(p_embeds + p * 128 + 64 + l * 4);
    float acc = se.x * pl.x + se.y * pl.y + se.z * pl.z + se.w * pl.w
              + re.x * ph.x + re.y * ph.y + re.z * ph.z + re.w * ph.w;
    acc += __shfl_xor(acc, 1, 64);
    acc += __shfl_xor(acc, 2, 64);
    acc += __shfl_xor(acc, 4, 64);
    acc += __shfl_xor(acc, 8, 64);
    if (l == 0) out[i] = 1.0f / (1.0f + __expf(-acc));
}

extern "C" void kernel_launch(void* const* d_in, const int* in_sizes, int n_in,
                              void* d_out, int out_size, void* d_ws, size_t ws_size,
                              hipStream_t stream) {
    const int*   X        = (const int*)d_in[0];
    const float* s_embeds = (const float*)d_in[1];
    const float* r_embeds = (const float*)d_in[2];
    const float* p_embeds = (const float*)d_in[3];
    float* out = (float*)d_out;
    const int n = in_sizes[0] / 4;

    if (ws_size < WS_NEED) {
        direct_kernel<<<(n + 15) / 16, 256, 0, stream>>>(
            X, s_embeds, r_embeds, p_embeds, out, n);
        return;
    }

    int* cursors = (int*)d_ws;
    int4* packed = reinterpret_cast<int4*>((char*)d_ws + PACKED_OFF_B);

    zero_kernel<<<1, 256, 0, stream>>>(reinterpret_cast<int4*>(cursors));
    bin_kernel<<<(n + 1023) / 1024, 256, 0, stream>>>(
        X, n, cursors, packed, s_embeds, r_embeds, p_embeds, out);
    compute_kernel<<<PG * SPLIT, 256, 0, stream>>>(
        cursors, packed, s_embeds, r_embeds, p_embeds, out);
}